// Round 10
// baseline (30.366 us; speedup 1.0000x reference)
//
#include <hip/hip_runtime.h>

#define NB 32
#define NT 2048
#define TOUT 512
#define ND 256
#define TILE_M 16
#define BLK_J 32  // j-rows per fused block (2 tiles of 16)
#define LDA 264   // ushort stride for pooled rows in LDS (256+8): 528B, 16B-aligned
#define LDH 264   // float stride for h rows

typedef __attribute__((ext_vector_type(4))) float f32x4;
typedef __attribute__((ext_vector_type(8))) short bf16x8;
typedef __attribute__((ext_vector_type(4))) unsigned short u16x4;

__device__ __forceinline__ unsigned short f2b(float f) {
    unsigned int u = __builtin_bit_cast(unsigned int, f);
    return (unsigned short)((u + 0x7FFFu + ((u >> 16) & 1u)) >> 16);  // RNE
}

// tanh-form GELU as sigmoid: x * sigmoid(2*sqrt(2/pi)*(x + 0.044715 x^3)).
// Max abs deviation from exact-erf GELU ~3e-4 << 0.14 error budget.
__device__ __forceinline__ float gelu_fast(float x) {
    float x2 = x * x;
    float p  = x * fmaf(x2, 0.044715f, 1.0f);
    float a  = fminf(1.5957691216f * p, 80.0f);   // clamp: exp overflow guard
    float e  = __expf(a);
    return x * __fdividef(e, e + 1.0f);
}

__device__ __forceinline__ float gelu_exact(float x) {
    return 0.5f * x * (1.0f + erff(x * 0.70710678118654752440f));
}

template <int K>
__device__ __forceinline__ f32x4 sumK(const float* p) {
    f32x4 v[K];
    #pragma unroll
    for (int t = 0; t < K; ++t)
        v[t] = *reinterpret_cast<const f32x4*>(p + (size_t)t * ND);
    f32x4 s = v[0];
    #pragma unroll
    for (int t = 1; t < K; ++t) s += v[t];
    return s;
}

// W f32 -> bf16 FRAGMENT-MAJOR: wbF[((et*8+kk)*64 + lane)*8 + i] =
//   W[e = et*16 + (lane&15)][k = kk*32 + (lane>>4)*8 + i]
__global__ __launch_bounds__(512)
void cvt_w_kernel(const float* __restrict__ wf, unsigned short* __restrict__ wbF) {
    const int gid = blockIdx.x * 512 + (int)threadIdx.x;   // 8192 threads
    const int l   = gid & 63;
    const int kk  = (gid >> 6) & 7;
    const int et  = gid >> 9;                 // 0..15
    const int e   = et * 16 + (l & 15);
    const int k   = kk * 32 + (l >> 4) * 8;
    f32x4 a = *reinterpret_cast<const f32x4*>(wf + e * ND + k);
    f32x4 c = *reinterpret_cast<const f32x4*>(wf + e * ND + k + 4);
    u16x4 p0, p1;
    p0.x = f2b(a.x); p0.y = f2b(a.y); p0.z = f2b(a.z); p0.w = f2b(a.w);
    p1.x = f2b(c.x); p1.y = f2b(c.y); p1.z = f2b(c.z); p1.w = f2b(c.w);
    *reinterpret_cast<u16x4*>(wbF + (size_t)gid * 8)     = p0;
    *reinterpret_cast<u16x4*>(wbF + (size_t)gid * 8 + 4) = p1;
}

// Fused, software-pipelined within the block:
//   pool_t0 | bar | {pool_t1 || GEMM+GELU_t0} | bar | {GEMM+GELU_t1 || LN_t0} | bar | LN_t1
__global__ __launch_bounds__(512, 2)
void fused_kernel(const float* __restrict__ mu,
                  const int* __restrict__ lens,
                  const int* __restrict__ olens,
                  const unsigned short* __restrict__ wbF,
                  const float* __restrict__ gamma,
                  const float* __restrict__ beta,
                  float* __restrict__ out)
{
    __shared__ unsigned short a_lds[2][TILE_M * LDA];  // pooled rows, bf16
    __shared__ float h_lds[2][TILE_M * LDH];           // post-GELU rows, f32

    const int b    = blockIdx.x;
    const int j0   = blockIdx.y * BLK_J;
    const int tid  = (int)threadIdx.x;
    const int lane = tid & 63;
    const int wv   = tid >> 6;     // 0..7
    const int r    = lane & 15;
    const int kg   = lane >> 4;

    // ---- W fragments -> registers (once per block; coalesced 1KB loads) ----
    bf16x8 wreg[8][2];
    #pragma unroll
    for (int kk = 0; kk < 8; ++kk)
        #pragma unroll
        for (int p = 0; p < 2; ++p) {
            const int et = wv * 2 + p;
            wreg[kk][p] = *reinterpret_cast<const bf16x8*>(
                wbF + (size_t)((et * 8 + kk) * 64 + lane) * 8);
        }

    const int L = lens[b];
    const int O = olens[b];
    const f32x4 g4 = *reinterpret_cast<const f32x4*>(&gamma[lane * 4]);
    const f32x4 b4 = *reinterpret_cast<const f32x4*>(&beta[lane * 4]);

    // ---- pool tile0 (rows 0..15): exact-count switch, 2 rows/wave ----
    #pragma unroll
    for (int i = 0; i < 2; ++i) {
        const int m = wv + i * 8;
        const int j = j0 + m;
        f32x4 s = {0.f, 0.f, 0.f, 0.f};
        if (j < O) {
            const int st  = (j * L) / O;
            const int en  = ((j + 1) * L + O - 1) / O;
            const int cnt = en - st;                 // wave-uniform, in [2, 9]
            const float* p = mu + (size_t)(b * NT + st) * ND + lane * 4;
            switch (cnt) {
                case 2: s = sumK<2>(p); break;
                case 3: s = sumK<3>(p); break;
                case 4: s = sumK<4>(p); break;
                case 5: s = sumK<5>(p); break;
                case 6: s = sumK<6>(p); break;
                case 7: s = sumK<7>(p); break;
                case 8: s = sumK<8>(p); break;
                case 9: s = sumK<9>(p); break;
                default:
                    for (int t = 0; t < cnt; ++t)
                        s += *reinterpret_cast<const f32x4*>(p + (size_t)t * ND);
                    break;
            }
            s *= 1.0f / (float)cnt;
        }
        u16x4 q;
        q.x = f2b(s.x); q.y = f2b(s.y); q.z = f2b(s.z); q.w = f2b(s.w);
        *reinterpret_cast<u16x4*>(&a_lds[0][m * LDA + lane * 4]) = q;
    }
    __syncthreads();

    // ---- pool tile1 (rows 16..31), branch-free clamped-8 loads (issued early),
    //      overlapped by the compiler with GEMM+GELU of tile0 below ----
    #pragma unroll
    for (int i = 0; i < 2; ++i) {
        const int m1 = wv + i * 8;           // row within tile1
        const int j  = j0 + 16 + m1;
        f32x4 s = {0.f, 0.f, 0.f, 0.f};
        int cnt = 0; float inv = 0.f;
        const float* bp = mu + (size_t)b * NT * ND + lane * 4;
        if (j < O) {
            const int st = (j * L) / O;
            const int en = ((j + 1) * L + O - 1) / O;
            cnt = en - st;
            inv = 1.0f / (float)cnt;
            bp  = mu + (size_t)(b * NT + st) * ND + lane * 4;
        }
        const int cm1 = (cnt > 0) ? (cnt - 1) : 0;
        f32x4 v[8];
        #pragma unroll
        for (int t = 0; t < 8; ++t) {
            const int tc = (t < cm1) ? t : cm1;
            v[t] = *reinterpret_cast<const f32x4*>(bp + (size_t)tc * ND);
        }
        #pragma unroll
        for (int t = 0; t < 8; ++t) {
            const float w = (t < cnt) ? inv : 0.f;
            s += v[t] * w;
        }
        if (cnt == 9)   // rare 9th frame, wave-uniform
            s += *reinterpret_cast<const f32x4*>(bp + (size_t)8 * ND) * inv;
        u16x4 q;
        q.x = f2b(s.x); q.y = f2b(s.y); q.z = f2b(s.z); q.w = f2b(s.w);
        *reinterpret_cast<u16x4*>(&a_lds[1][m1 * LDA + lane * 4]) = q;
    }

    // ---- GEMM + GELU tile0 (reads a[0], writes h[0]) ----
    {
        f32x4 acc[2];
        acc[0] = (f32x4){0.f, 0.f, 0.f, 0.f};
        acc[1] = (f32x4){0.f, 0.f, 0.f, 0.f};
        #pragma unroll
        for (int kk = 0; kk < 8; ++kk) {
            const int k0 = kk * 32 + kg * 8;
            bf16x8 af = *reinterpret_cast<const bf16x8*>(&a_lds[0][r * LDA + k0]);
            acc[0] = __builtin_amdgcn_mfma_f32_16x16x32_bf16(af, wreg[kk][0], acc[0], 0, 0, 0);
            acc[1] = __builtin_amdgcn_mfma_f32_16x16x32_bf16(af, wreg[kk][1], acc[1], 0, 0, 0);
        }
        #pragma unroll
        for (int p = 0; p < 2; ++p) {
            const int col = wv * 32 + p * 16 + r;
            #pragma unroll
            for (int q = 0; q < 4; ++q)
                h_lds[0][(kg * 4 + q) * LDH + col] = gelu_fast(acc[p][q]);
        }
    }
    __syncthreads();

    // ---- GEMM + GELU tile1 (reads a[1], writes h[1]) ----
    {
        f32x4 acc[2];
        acc[0] = (f32x4){0.f, 0.f, 0.f, 0.f};
        acc[1] = (f32x4){0.f, 0.f, 0.f, 0.f};
        #pragma unroll
        for (int kk = 0; kk < 8; ++kk) {
            const int k0 = kk * 32 + kg * 8;
            bf16x8 af = *reinterpret_cast<const bf16x8*>(&a_lds[1][r * LDA + k0]);
            acc[0] = __builtin_amdgcn_mfma_f32_16x16x32_bf16(af, wreg[kk][0], acc[0], 0, 0, 0);
            acc[1] = __builtin_amdgcn_mfma_f32_16x16x32_bf16(af, wreg[kk][1], acc[1], 0, 0, 0);
        }
        #pragma unroll
        for (int p = 0; p < 2; ++p) {
            const int col = wv * 32 + p * 16 + r;
            #pragma unroll
            for (int q = 0; q < 4; ++q)
                h_lds[1][(kg * 4 + q) * LDH + col] = gelu_fast(acc[p][q]);
        }
    }

    // ---- LayerNorm tile0 (reads h[0]) — overlaps tile1's MFMA above ----
    #pragma unroll
    for (int i = 0; i < 2; ++i) {
        const int m = wv + i * 8;
        f32x4 v = *reinterpret_cast<const f32x4*>(&h_lds[0][m * LDH + lane * 4]);
        float s  = v.x + v.y + v.z + v.w;
        float sq = v.x * v.x + v.y * v.y + v.z * v.z + v.w * v.w;
        #pragma unroll
        for (int off = 32; off > 0; off >>= 1) {
            s  += __shfl_xor(s, off, 64);
            sq += __shfl_xor(sq, off, 64);
        }
        const float mean = s * (1.0f / 256.0f);
        const float var  = sq * (1.0f / 256.0f) - mean * mean;
        const float rs   = rsqrtf(var + 1e-5f);
        f32x4 o = (v - mean) * rs * g4 + b4;
        *reinterpret_cast<f32x4*>(&out[((size_t)(b * TOUT) + j0 + m) * ND + lane * 4]) = o;
    }
    __syncthreads();

    // ---- LayerNorm tile1 ----
    #pragma unroll
    for (int i = 0; i < 2; ++i) {
        const int m = wv + i * 8;
        f32x4 v = *reinterpret_cast<const f32x4*>(&h_lds[1][m * LDH + lane * 4]);
        float s  = v.x + v.y + v.z + v.w;
        float sq = v.x * v.x + v.y * v.y + v.z * v.z + v.w * v.w;
        #pragma unroll
        for (int off = 32; off > 0; off >>= 1) {
            s  += __shfl_xor(s, off, 64);
            sq += __shfl_xor(sq, off, 64);
        }
        const float mean = s * (1.0f / 256.0f);
        const float var  = sq * (1.0f / 256.0f) - mean * mean;
        const float rs   = rsqrtf(var + 1e-5f);
        f32x4 o = (v - mean) * rs * g4 + b4;
        *reinterpret_cast<f32x4*>(&out[((size_t)(b * TOUT) + j0 + 16 + m) * ND + lane * 4]) = o;
    }
}

// Fallback (ws too small): monolithic fused kernel, dynamic pooling loop. Slow but correct.
__global__ __launch_bounds__(256, 4)
void fused_fallback(const float* __restrict__ mu,
                    const int* __restrict__ lens,
                    const int* __restrict__ olens,
                    const float* __restrict__ wf,
                    const float* __restrict__ gamma,
                    const float* __restrict__ beta,
                    float* __restrict__ out)
{
    __shared__ unsigned short a_lds[TILE_M * LDA];
    __shared__ float h_lds[TILE_M * LDH];

    const int b    = blockIdx.x;
    const int j0   = blockIdx.y * TILE_M;
    const int tid  = (int)threadIdx.x;
    const int lane = tid & 63;
    const int wv   = tid >> 6;
    const int L = lens[b];
    const int O = olens[b];

    for (int m = wv; m < TILE_M; m += 4) {
        const int j = j0 + m;
        f32x4 acc = {0.f, 0.f, 0.f, 0.f};
        if (j < O) {
            const int s = (j * L) / O;
            const int e = ((j + 1) * L + O - 1) / O;
            const float* src = mu + (size_t)(b * NT + s) * ND + lane * 4;
            for (int t = s; t < e; ++t) {
                acc += *reinterpret_cast<const f32x4*>(src);
                src += ND;
            }
            acc *= (1.0f / (float)(e - s));
        }
        u16x4 p;
        p.x = f2b(acc.x); p.y = f2b(acc.y); p.z = f2b(acc.z); p.w = f2b(acc.w);
        *reinterpret_cast<u16x4*>(&a_lds[m * LDA + lane * 4]) = p;
    }
    __syncthreads();

    const int r  = lane & 15;
    const int kg = lane >> 4;
    const int e0 = wv * 64;
    f32x4 acc[4];
    #pragma unroll
    for (int c = 0; c < 4; ++c) acc[c] = (f32x4){0.f, 0.f, 0.f, 0.f};
    #pragma unroll
    for (int kk = 0; kk < 8; ++kk) {
        const int k0 = kk * 32 + kg * 8;
        bf16x8 af = *reinterpret_cast<const bf16x8*>(&a_lds[r * LDA + k0]);
        #pragma unroll
        for (int ct = 0; ct < 4; ++ct) {
            const int e = e0 + ct * 16 + r;
            f32x4 w0 = *reinterpret_cast<const f32x4*>(&wf[e * ND + k0]);
            f32x4 w1 = *reinterpret_cast<const f32x4*>(&wf[e * ND + k0 + 4]);
            union { bf16x8 v; unsigned short u[8]; } cv;
            cv.u[0] = f2b(w0.x); cv.u[1] = f2b(w0.y);
            cv.u[2] = f2b(w0.z); cv.u[3] = f2b(w0.w);
            cv.u[4] = f2b(w1.x); cv.u[5] = f2b(w1.y);
            cv.u[6] = f2b(w1.z); cv.u[7] = f2b(w1.w);
            acc[ct] = __builtin_amdgcn_mfma_f32_16x16x32_bf16(af, cv.v, acc[ct], 0, 0, 0);
        }
    }
    #pragma unroll
    for (int ct = 0; ct < 4; ++ct) {
        const int col  = e0 + ct * 16 + r;
        const int row0 = kg * 4;
        #pragma unroll
        for (int q = 0; q < 4; ++q)
            h_lds[(row0 + q) * LDH + col] = gelu_exact(acc[ct][q]);
    }
    __syncthreads();
    const f32x4 g4 = *reinterpret_cast<const f32x4*>(&gamma[lane * 4]);
    const f32x4 b4 = *reinterpret_cast<const f32x4*>(&beta[lane * 4]);
    #pragma unroll
    for (int i = 0; i < 4; ++i) {
        const int m = wv + i * 4;
        f32x4 v = *reinterpret_cast<const f32x4*>(&h_lds[m * LDH + lane * 4]);
        float s  = v.x + v.y + v.z + v.w;
        float sq = v.x * v.x + v.y * v.y + v.z * v.z + v.w * v.w;
        #pragma unroll
        for (int off = 32; off > 0; off >>= 1) {
            s  += __shfl_xor(s, off, 64);
            sq += __shfl_xor(sq, off, 64);
        }
        const float mean = s * (1.0f / 256.0f);
        const float var  = sq * (1.0f / 256.0f) - mean * mean;
        const float rs   = rsqrtf(var + 1e-5f);
        f32x4 o = (v - mean) * rs * g4 + b4;
        *reinterpret_cast<f32x4*>(&out[((size_t)(b * TOUT) + j0 + m) * ND + lane * 4]) = o;
    }
}

extern "C" void kernel_launch(void* const* d_in, const int* in_sizes, int n_in,
                              void* d_out, int out_size, void* d_ws, size_t ws_size,
                              hipStream_t stream) {
    const float* mu    = (const float*)d_in[0];
    const int*   lens  = (const int*)d_in[1];
    const int*   olens = (const int*)d_in[2];
    const float* wf    = (const float*)d_in[3];
    const float* gamma = (const float*)d_in[4];
    const float* beta  = (const float*)d_in[5];
    float* out = (float*)d_out;

    const size_t need = (size_t)ND * ND * sizeof(unsigned short);  // 128 KB

    if (ws_size >= need) {
        unsigned short* wbF = (unsigned short*)d_ws;
        cvt_w_kernel<<<dim3(16), dim3(512), 0, stream>>>(wf, wbF);
        fused_kernel<<<dim3(NB, TOUT / BLK_J), dim3(512), 0, stream>>>(
            mu, lens, olens, wbF, gamma, beta, out);
    } else {
        fused_fallback<<<dim3(NB, TOUT / TILE_M), dim3(256), 0, stream>>>(
            mu, lens, olens, wf, gamma, beta, out);
    }
}

// Round 11
// 27.299 us; speedup vs baseline: 1.1123x; 1.1123x over previous
//
#include <hip/hip_runtime.h>

#define NB 32
#define NT 2048
#define TOUT 512
#define ND 256
#define TILE_M 16
#define BLK_J 32  // j-rows per fused block (2 tiles of 16)
#define LDA 264   // ushort stride for pooled rows in LDS (256+8): 528B, 16B-aligned
#define LDH 268   // float stride for h rows: row-diff-4 banks offset 16 -> 2-way (free)

typedef __attribute__((ext_vector_type(4))) float f32x4;
typedef __attribute__((ext_vector_type(8))) short bf16x8;
typedef __attribute__((ext_vector_type(4))) unsigned short u16x4;

__device__ __forceinline__ unsigned short f2b(float f) {
    unsigned int u = __builtin_bit_cast(unsigned int, f);
    return (unsigned short)((u + 0x7FFFu + ((u >> 16) & 1u)) >> 16);  // RNE
}

// tanh-form GELU as sigmoid: x * sigmoid(2*sqrt(2/pi)*(x + 0.044715 x^3)).
// Max abs deviation from exact-erf GELU ~3e-4 << 0.14 error budget.
__device__ __forceinline__ float gelu_fast(float x) {
    float x2 = x * x;
    float p  = x * fmaf(x2, 0.044715f, 1.0f);
    float a  = fminf(1.5957691216f * p, 80.0f);   // clamp: exp overflow guard
    float e  = __expf(a);
    return x * __fdividef(e, e + 1.0f);
}

__device__ __forceinline__ float gelu_exact(float x) {
    return 0.5f * x * (1.0f + erff(x * 0.70710678118654752440f));
}

template <int K>
__device__ __forceinline__ f32x4 sumK(const float* p) {
    f32x4 v[K];
    #pragma unroll
    for (int t = 0; t < K; ++t)
        v[t] = *reinterpret_cast<const f32x4*>(p + (size_t)t * ND);
    f32x4 s = v[0];
    #pragma unroll
    for (int t = 1; t < K; ++t) s += v[t];
    return s;
}

// W f32 -> bf16 FRAGMENT-MAJOR: wbF[((et*8+kk)*64 + lane)*8 + i] =
//   W[e = et*16 + (lane&15)][k = kk*32 + (lane>>4)*8 + i]
__global__ __launch_bounds__(512)
void cvt_w_kernel(const float* __restrict__ wf, unsigned short* __restrict__ wbF) {
    const int gid = blockIdx.x * 512 + (int)threadIdx.x;   // 8192 threads
    const int l   = gid & 63;
    const int kk  = (gid >> 6) & 7;
    const int et  = gid >> 9;                 // 0..15
    const int e   = et * 16 + (l & 15);
    const int k   = kk * 32 + (l >> 4) * 8;
    f32x4 a = *reinterpret_cast<const f32x4*>(wf + e * ND + k);
    f32x4 c = *reinterpret_cast<const f32x4*>(wf + e * ND + k + 4);
    u16x4 p0, p1;
    p0.x = f2b(a.x); p0.y = f2b(a.y); p0.z = f2b(a.z); p0.w = f2b(a.w);
    p1.x = f2b(c.x); p1.y = f2b(c.y); p1.z = f2b(c.z); p1.w = f2b(c.w);
    *reinterpret_cast<u16x4*>(wbF + (size_t)gid * 8)     = p0;
    *reinterpret_cast<u16x4*>(wbF + (size_t)gid * 8 + 4) = p1;
}

// Fused: pool 32 rows -> [wreg load + PIN] -> barrier -> MFMA x2 -> GELU -> LN.
// Grid (NB, TOUT/32) = 512 blocks x 512 thr -> 2 blocks/CU.
// W is loaded ONCE per block and pinned in VGPRs via inline-asm so the
// compiler cannot sink/re-load it per tile (R10 showed it does: VGPR=68).
__global__ __launch_bounds__(512, 2)
void fused_kernel(const float* __restrict__ mu,
                  const int* __restrict__ lens,
                  const int* __restrict__ olens,
                  const unsigned short* __restrict__ wbF,
                  const float* __restrict__ gamma,
                  const float* __restrict__ beta,
                  float* __restrict__ out)
{
    __shared__ unsigned short a_lds[2][TILE_M * LDA];  // pooled rows, bf16
    __shared__ float h_lds[2][TILE_M * LDH];           // post-GELU rows, f32

    const int b    = blockIdx.x;
    const int j0   = blockIdx.y * BLK_J;
    const int tid  = (int)threadIdx.x;
    const int lane = tid & 63;
    const int wv   = tid >> 6;     // 0..7, e-range [wv*32, wv*32+32)
    const int r    = lane & 15;
    const int kg   = lane >> 4;

    const int L = lens[b];
    const int O = olens[b];

    // ---- inline ragged pool: 4 rows per wave (32 rows), exact-count loads ----
    #pragma unroll
    for (int i = 0; i < 4; ++i) {
        const int m = wv + i * 8;          // 0..31
        const int j = j0 + m;
        f32x4 s = {0.f, 0.f, 0.f, 0.f};
        if (j < O) {
            const int st  = (j * L) / O;
            const int en  = ((j + 1) * L + O - 1) / O;
            const int cnt = en - st;                 // wave-uniform, in [2, 9]
            const float* p = mu + (size_t)(b * NT + st) * ND + lane * 4;
            switch (cnt) {                           // uniform scalar branch
                case 2: s = sumK<2>(p); break;
                case 3: s = sumK<3>(p); break;
                case 4: s = sumK<4>(p); break;
                case 5: s = sumK<5>(p); break;
                case 6: s = sumK<6>(p); break;
                case 7: s = sumK<7>(p); break;
                case 8: s = sumK<8>(p); break;
                case 9: s = sumK<9>(p); break;
                default:
                    for (int t = 0; t < cnt; ++t)
                        s += *reinterpret_cast<const f32x4*>(p + (size_t)t * ND);
                    break;
            }
            s *= 1.0f / (float)cnt;
        }
        u16x4 q;
        q.x = f2b(s.x); q.y = f2b(s.y); q.z = f2b(s.z); q.w = f2b(s.w);
        *reinterpret_cast<u16x4*>(&a_lds[m >> 4][(m & 15) * LDA + lane * 4]) = q;
    }

    // ---- W fragments -> registers, loads overlap the barrier drain; PIN them
    //      so they are materialized once and stay resident across both tiles ----
    bf16x8 wreg[8][2];
    #pragma unroll
    for (int kk = 0; kk < 8; ++kk)
        #pragma unroll
        for (int p = 0; p < 2; ++p) {
            const int et = wv * 2 + p;
            wreg[kk][p] = *reinterpret_cast<const bf16x8*>(
                wbF + (size_t)((et * 8 + kk) * 64 + lane) * 8);
        }
    #pragma unroll
    for (int kk = 0; kk < 8; ++kk)
        asm volatile("" : "+v"(wreg[kk][0]), "+v"(wreg[kk][1]));

    __syncthreads();

    // ---- GEMM + GELU for both 16-row tiles (wreg reused from registers) ----
    #pragma unroll
    for (int t = 0; t < 2; ++t) {
        f32x4 acc[2];
        acc[0] = (f32x4){0.f, 0.f, 0.f, 0.f};
        acc[1] = (f32x4){0.f, 0.f, 0.f, 0.f};
        #pragma unroll
        for (int kk = 0; kk < 8; ++kk) {
            const int k0 = kk * 32 + kg * 8;
            bf16x8 af = *reinterpret_cast<const bf16x8*>(&a_lds[t][r * LDA + k0]);
            acc[0] = __builtin_amdgcn_mfma_f32_16x16x32_bf16(af, wreg[kk][0], acc[0], 0, 0, 0);
            acc[1] = __builtin_amdgcn_mfma_f32_16x16x32_bf16(af, wreg[kk][1], acc[1], 0, 0, 0);
        }
        // GELU; C/D layout (verified m89): col = lane&15, row = (lane>>4)*4 + q
        #pragma unroll
        for (int p = 0; p < 2; ++p) {
            const int col = wv * 32 + p * 16 + r;
            #pragma unroll
            for (int q = 0; q < 4; ++q)
                h_lds[t][(kg * 4 + q) * LDH + col] = gelu_fast(acc[p][q]);
        }
    }
    __syncthreads();

    // ---- LayerNorm over D: 4 rows/wave across both buffers, coalesced store ----
    const f32x4 g4 = *reinterpret_cast<const f32x4*>(&gamma[lane * 4]);
    const f32x4 b4 = *reinterpret_cast<const f32x4*>(&beta[lane * 4]);
    #pragma unroll
    for (int i = 0; i < 4; ++i) {
        const int m = wv + i * 8;          // 0..31
        f32x4 v = *reinterpret_cast<const f32x4*>(&h_lds[m >> 4][(m & 15) * LDH + lane * 4]);
        float s  = v.x + v.y + v.z + v.w;
        float sq = v.x * v.x + v.y * v.y + v.z * v.z + v.w * v.w;
        #pragma unroll
        for (int off = 32; off > 0; off >>= 1) {
            s  += __shfl_xor(s, off, 64);
            sq += __shfl_xor(sq, off, 64);
        }
        const float mean = s * (1.0f / 256.0f);
        const float var  = sq * (1.0f / 256.0f) - mean * mean;
        const float rs   = rsqrtf(var + 1e-5f);
        f32x4 o = (v - mean) * rs * g4 + b4;
        *reinterpret_cast<f32x4*>(&out[((size_t)(b * TOUT) + j0 + m) * ND + lane * 4]) = o;
    }
}

// Fallback (ws too small): monolithic fused kernel, dynamic pooling loop. Slow but correct.
__global__ __launch_bounds__(256, 4)
void fused_fallback(const float* __restrict__ mu,
                    const int* __restrict__ lens,
                    const int* __restrict__ olens,
                    const float* __restrict__ wf,
                    const float* __restrict__ gamma,
                    const float* __restrict__ beta,
                    float* __restrict__ out)
{
    __shared__ unsigned short a_lds[TILE_M * LDA];
    __shared__ float h_lds[TILE_M * LDH];

    const int b    = blockIdx.x;
    const int j0   = blockIdx.y * TILE_M;
    const int tid  = (int)threadIdx.x;
    const int lane = tid & 63;
    const int wv   = tid >> 6;
    const int L = lens[b];
    const int O = olens[b];

    for (int m = wv; m < TILE_M; m += 4) {
        const int j = j0 + m;
        f32x4 acc = {0.f, 0.f, 0.f, 0.f};
        if (j < O) {
            const int s = (j * L) / O;
            const int e = ((j + 1) * L + O - 1) / O;
            const float* src = mu + (size_t)(b * NT + s) * ND + lane * 4;
            for (int t = s; t < e; ++t) {
                acc += *reinterpret_cast<const f32x4*>(src);
                src += ND;
            }
            acc *= (1.0f / (float)(e - s));
        }
        u16x4 p;
        p.x = f2b(acc.x); p.y = f2b(acc.y); p.z = f2b(acc.z); p.w = f2b(acc.w);
        *reinterpret_cast<u16x4*>(&a_lds[m * LDA + lane * 4]) = p;
    }
    __syncthreads();

    const int r  = lane & 15;
    const int kg = lane >> 4;
    const int e0 = wv * 64;
    f32x4 acc[4];
    #pragma unroll
    for (int c = 0; c < 4; ++c) acc[c] = (f32x4){0.f, 0.f, 0.f, 0.f};
    #pragma unroll
    for (int kk = 0; kk < 8; ++kk) {
        const int k0 = kk * 32 + kg * 8;
        bf16x8 af = *reinterpret_cast<const bf16x8*>(&a_lds[r * LDA + k0]);
        #pragma unroll
        for (int ct = 0; ct < 4; ++ct) {
            const int e = e0 + ct * 16 + r;
            f32x4 w0 = *reinterpret_cast<const f32x4*>(&wf[e * ND + k0]);
            f32x4 w1 = *reinterpret_cast<const f32x4*>(&wf[e * ND + k0 + 4]);
            union { bf16x8 v; unsigned short u[8]; } cv;
            cv.u[0] = f2b(w0.x); cv.u[1] = f2b(w0.y);
            cv.u[2] = f2b(w0.z); cv.u[3] = f2b(w0.w);
            cv.u[4] = f2b(w1.x); cv.u[5] = f2b(w1.y);
            cv.u[6] = f2b(w1.z); cv.u[7] = f2b(w1.w);
            acc[ct] = __builtin_amdgcn_mfma_f32_16x16x32_bf16(af, cv.v, acc[ct], 0, 0, 0);
        }
    }
    #pragma unroll
    for (int ct = 0; ct < 4; ++ct) {
        const int col  = e0 + ct * 16 + r;
        const int row0 = kg * 4;
        #pragma unroll
        for (int q = 0; q < 4; ++q)
            h_lds[(row0 + q) * LDH + col] = gelu_exact(acc[ct][q]);
    }
    __syncthreads();
    const f32x4 g4 = *reinterpret_cast<const f32x4*>(&gamma[lane * 4]);
    const f32x4 b4 = *reinterpret_cast<const f32x4*>(&beta[lane * 4]);
    #pragma unroll
    for (int i = 0; i < 4; ++i) {
        const int m = wv + i * 4;
        f32x4 v = *reinterpret_cast<const f32x4*>(&h_lds[m * LDH + lane * 4]);
        float s  = v.x + v.y + v.z + v.w;
        float sq = v.x * v.x + v.y * v.y + v.z * v.z + v.w * v.w;
        #pragma unroll
        for (int off = 32; off > 0; off >>= 1) {
            s  += __shfl_xor(s, off, 64);
            sq += __shfl_xor(sq, off, 64);
        }
        const float mean = s * (1.0f / 256.0f);
        const float var  = sq * (1.0f / 256.0f) - mean * mean;
        const float rs   = rsqrtf(var + 1e-5f);
        f32x4 o = (v - mean) * rs * g4 + b4;
        *reinterpret_cast<f32x4*>(&out[((size_t)(b * TOUT) + j0 + m) * ND + lane * 4]) = o;
    }
}

extern "C" void kernel_launch(void* const* d_in, const int* in_sizes, int n_in,
                              void* d_out, int out_size, void* d_ws, size_t ws_size,
                              hipStream_t stream) {
    const float* mu    = (const float*)d_in[0];
    const int*   lens  = (const int*)d_in[1];
    const int*   olens = (const int*)d_in[2];
    const float* wf    = (const float*)d_in[3];
    const float* gamma = (const float*)d_in[4];
    const float* beta  = (const float*)d_in[5];
    float* out = (float*)d_out;

    const size_t need = (size_t)ND * ND * sizeof(unsigned short);  // 128 KB

    if (ws_size >= need) {
        unsigned short* wbF = (unsigned short*)d_ws;
        cvt_w_kernel<<<dim3(16), dim3(512), 0, stream>>>(wf, wbF);
        fused_kernel<<<dim3(NB, TOUT / BLK_J), dim3(512), 0, stream>>>(
            mu, lens, olens, wbF, gamma, beta, out);
    } else {
        fused_fallback<<<dim3(NB, TOUT / TILE_M), dim3(256), 0, stream>>>(
            mu, lens, olens, wf, gamma, beta, out);
    }
}

// Round 12
// 26.887 us; speedup vs baseline: 1.1294x; 1.0153x over previous
//
#include <hip/hip_runtime.h>

#define NB 32
#define NT 2048
#define TOUT 512
#define ND 256
#define TILE_M 16
#define LDA 264   // ushort stride for pooled rows in LDS (256+8): 528B, 16B-aligned
#define LDH 268   // float stride for h rows: scattered GELU writes -> 2-way banks (free)

typedef __attribute__((ext_vector_type(4))) float f32x4;
typedef __attribute__((ext_vector_type(8))) short bf16x8;
typedef __attribute__((ext_vector_type(4))) unsigned short u16x4;

__device__ __forceinline__ unsigned short f2b(float f) {
    unsigned int u = __builtin_bit_cast(unsigned int, f);
    return (unsigned short)((u + 0x7FFFu + ((u >> 16) & 1u)) >> 16);  // RNE
}

// tanh-form GELU as sigmoid: x * sigmoid(2*sqrt(2/pi)*(x + 0.044715 x^3)).
// Max abs deviation from exact-erf GELU ~3e-4 << 0.14 error budget (passed R10/R11).
__device__ __forceinline__ float gelu_fast(float x) {
    float x2 = x * x;
    float p  = x * fmaf(x2, 0.044715f, 1.0f);
    float a  = fminf(1.5957691216f * p, 80.0f);   // clamp: exp overflow guard
    float e  = __expf(a);
    return x * __fdividef(e, e + 1.0f);
}

__device__ __forceinline__ float gelu_exact(float x) {
    return 0.5f * x * (1.0f + erff(x * 0.70710678118654752440f));
}

template <int K>
__device__ __forceinline__ f32x4 sumK(const float* p) {
    f32x4 v[K];
    #pragma unroll
    for (int t = 0; t < K; ++t)
        v[t] = *reinterpret_cast<const f32x4*>(p + (size_t)t * ND);
    f32x4 s = v[0];
    #pragma unroll
    for (int t = 1; t < K; ++t) s += v[t];
    return s;
}

// W f32 -> bf16 FRAGMENT-MAJOR: wbF[((et*8+kk)*64 + lane)*8 + i] =
//   W[e = et*16 + (lane&15)][k = kk*32 + (lane>>4)*8 + i]
__global__ __launch_bounds__(512)
void cvt_w_kernel(const float* __restrict__ wf, unsigned short* __restrict__ wbF) {
    const int gid = blockIdx.x * 512 + (int)threadIdx.x;   // 8192 threads
    const int l   = gid & 63;
    const int kk  = (gid >> 6) & 7;
    const int et  = gid >> 9;                 // 0..15
    const int e   = et * 16 + (l & 15);
    const int k   = kk * 32 + (l >> 4) * 8;
    f32x4 a = *reinterpret_cast<const f32x4*>(wf + e * ND + k);
    f32x4 c = *reinterpret_cast<const f32x4*>(wf + e * ND + k + 4);
    u16x4 p0, p1;
    p0.x = f2b(a.x); p0.y = f2b(a.y); p0.z = f2b(a.z); p0.w = f2b(a.w);
    p1.x = f2b(c.x); p1.y = f2b(c.y); p1.z = f2b(c.z); p1.w = f2b(c.w);
    *reinterpret_cast<u16x4*>(wbF + (size_t)gid * 8)     = p0;
    *reinterpret_cast<u16x4*>(wbF + (size_t)gid * 8 + 4) = p1;
}

// Fused: pool 16 rows -> LDS(bf16) -> MFMA (fragment-major W, L1-warm reload) ->
// GELU -> LN -> out. Grid (NB, TOUT/16) = 1024 blocks x 512 thr.
// __launch_bounds__(512, 6): 6 waves/EU declared -> VGPR cap ~85 -> ~3 blocks/CU
// (24 waves/CU) vs the accidental 1-block/CU cap of R7-R11's (512, 2).
__global__ __launch_bounds__(512, 6)
void fused_kernel(const float* __restrict__ mu,
                  const int* __restrict__ lens,
                  const int* __restrict__ olens,
                  const unsigned short* __restrict__ wbF,
                  const float* __restrict__ gamma,
                  const float* __restrict__ beta,
                  float* __restrict__ out)
{
    __shared__ unsigned short a_lds[TILE_M * LDA];  // pooled rows, bf16 (8.4 KB)
    __shared__ float h_lds[TILE_M * LDH];           // post-GELU rows, f32 (17.2 KB)

    const int b    = blockIdx.x;
    const int j0   = blockIdx.y * TILE_M;
    const int tid  = (int)threadIdx.x;
    const int lane = tid & 63;
    const int wv   = tid >> 6;     // 0..7, e-range [wv*32, wv*32+32)
    const int r    = lane & 15;
    const int kg   = lane >> 4;

    const int L = lens[b];
    const int O = olens[b];

    // ---- inline ragged pool: 2 rows per wave (16 rows), exact-count loads ----
    #pragma unroll
    for (int i = 0; i < 2; ++i) {
        const int m = wv + i * 8;          // 0..15
        const int j = j0 + m;
        f32x4 s = {0.f, 0.f, 0.f, 0.f};
        if (j < O) {
            const int st  = (j * L) / O;
            const int en  = ((j + 1) * L + O - 1) / O;
            const int cnt = en - st;                 // wave-uniform, in [2, 9]
            const float* p = mu + (size_t)(b * NT + st) * ND + lane * 4;
            switch (cnt) {                           // uniform scalar branch
                case 2: s = sumK<2>(p); break;
                case 3: s = sumK<3>(p); break;
                case 4: s = sumK<4>(p); break;
                case 5: s = sumK<5>(p); break;
                case 6: s = sumK<6>(p); break;
                case 7: s = sumK<7>(p); break;
                case 8: s = sumK<8>(p); break;
                case 9: s = sumK<9>(p); break;
                default:
                    for (int t = 0; t < cnt; ++t)
                        s += *reinterpret_cast<const f32x4*>(p + (size_t)t * ND);
                    break;
            }
            s *= 1.0f / (float)cnt;
        }
        u16x4 q;
        q.x = f2b(s.x); q.y = f2b(s.y); q.z = f2b(s.z); q.w = f2b(s.w);
        *reinterpret_cast<u16x4*>(&a_lds[m * LDA + lane * 4]) = q;
    }
    __syncthreads();

    // ---- GEMM: 16 MFMA from LDS-A x fragment-major W (compiler-placed loads,
    //      L1-warm after first generation; reload is perf-neutral per R8-R11) ----
    f32x4 acc[2];
    acc[0] = (f32x4){0.f, 0.f, 0.f, 0.f};
    acc[1] = (f32x4){0.f, 0.f, 0.f, 0.f};
    #pragma unroll
    for (int kk = 0; kk < 8; ++kk) {
        const int k0 = kk * 32 + kg * 8;
        bf16x8 af = *reinterpret_cast<const bf16x8*>(&a_lds[r * LDA + k0]);
        bf16x8 w0 = *reinterpret_cast<const bf16x8*>(
            wbF + (size_t)(((wv * 2 + 0) * 8 + kk) * 64 + lane) * 8);
        bf16x8 w1 = *reinterpret_cast<const bf16x8*>(
            wbF + (size_t)(((wv * 2 + 1) * 8 + kk) * 64 + lane) * 8);
        acc[0] = __builtin_amdgcn_mfma_f32_16x16x32_bf16(af, w0, acc[0], 0, 0, 0);
        acc[1] = __builtin_amdgcn_mfma_f32_16x16x32_bf16(af, w1, acc[1], 0, 0, 0);
    }

    // ---- GELU; C/D layout (verified m89): col = lane&15, row = (lane>>4)*4 + q
    #pragma unroll
    for (int p = 0; p < 2; ++p) {
        const int col = wv * 32 + p * 16 + r;
        #pragma unroll
        for (int q = 0; q < 4; ++q)
            h_lds[(kg * 4 + q) * LDH + col] = gelu_fast(acc[p][q]);
    }
    __syncthreads();

    // ---- LayerNorm over D: 2 rows/wave, coalesced store ----
    const f32x4 g4 = *reinterpret_cast<const f32x4*>(&gamma[lane * 4]);
    const f32x4 b4 = *reinterpret_cast<const f32x4*>(&beta[lane * 4]);
    #pragma unroll
    for (int i = 0; i < 2; ++i) {
        const int m = wv + i * 8;
        f32x4 v = *reinterpret_cast<const f32x4*>(&h_lds[m * LDH + lane * 4]);
        float s  = v.x + v.y + v.z + v.w;
        float sq = v.x * v.x + v.y * v.y + v.z * v.z + v.w * v.w;
        #pragma unroll
        for (int off = 32; off > 0; off >>= 1) {
            s  += __shfl_xor(s, off, 64);
            sq += __shfl_xor(sq, off, 64);
        }
        const float mean = s * (1.0f / 256.0f);
        const float var  = sq * (1.0f / 256.0f) - mean * mean;
        const float rs   = rsqrtf(var + 1e-5f);
        f32x4 o = (v - mean) * rs * g4 + b4;
        *reinterpret_cast<f32x4*>(&out[((size_t)(b * TOUT) + j0 + m) * ND + lane * 4]) = o;
    }
}

// Fallback (ws too small): monolithic fused kernel, dynamic pooling loop. Slow but correct.
__global__ __launch_bounds__(256, 4)
void fused_fallback(const float* __restrict__ mu,
                    const int* __restrict__ lens,
                    const int* __restrict__ olens,
                    const float* __restrict__ wf,
                    const float* __restrict__ gamma,
                    const float* __restrict__ beta,
                    float* __restrict__ out)
{
    __shared__ unsigned short a_lds[TILE_M * LDA];
    __shared__ float h_lds[TILE_M * LDH];

    const int b    = blockIdx.x;
    const int j0   = blockIdx.y * TILE_M;
    const int tid  = (int)threadIdx.x;
    const int lane = tid & 63;
    const int wv   = tid >> 6;
    const int L = lens[b];
    const int O = olens[b];

    for (int m = wv; m < TILE_M; m += 4) {
        const int j = j0 + m;
        f32x4 acc = {0.f, 0.f, 0.f, 0.f};
        if (j < O) {
            const int s = (j * L) / O;
            const int e = ((j + 1) * L + O - 1) / O;
            const float* src = mu + (size_t)(b * NT + s) * ND + lane * 4;
            for (int t = s; t < e; ++t) {
                acc += *reinterpret_cast<const f32x4*>(src);
                src += ND;
            }
            acc *= (1.0f / (float)(e - s));
        }
        u16x4 p;
        p.x = f2b(acc.x); p.y = f2b(acc.y); p.z = f2b(acc.z); p.w = f2b(acc.w);
        *reinterpret_cast<u16x4*>(&a_lds[m * LDA + lane * 4]) = p;
    }
    __syncthreads();

    const int r  = lane & 15;
    const int kg = lane >> 4;
    const int e0 = wv * 64;
    f32x4 acc[4];
    #pragma unroll
    for (int c = 0; c < 4; ++c) acc[c] = (f32x4){0.f, 0.f, 0.f, 0.f};
    #pragma unroll
    for (int kk = 0; kk < 8; ++kk) {
        const int k0 = kk * 32 + kg * 8;
        bf16x8 af = *reinterpret_cast<const bf16x8*>(&a_lds[r * LDA + k0]);
        #pragma unroll
        for (int ct = 0; ct < 4; ++ct) {
            const int e = e0 + ct * 16 + r;
            f32x4 w0 = *reinterpret_cast<const f32x4*>(&wf[e * ND + k0]);
            f32x4 w1 = *reinterpret_cast<const f32x4*>(&wf[e * ND + k0 + 4]);
            union { bf16x8 v; unsigned short u[8]; } cv;
            cv.u[0] = f2b(w0.x); cv.u[1] = f2b(w0.y);
            cv.u[2] = f2b(w0.z); cv.u[3] = f2b(w0.w);
            cv.u[4] = f2b(w1.x); cv.u[5] = f2b(w1.y);
            cv.u[6] = f2b(w1.z); cv.u[7] = f2b(w1.w);
            acc[ct] = __builtin_amdgcn_mfma_f32_16x16x32_bf16(af, cv.v, acc[ct], 0, 0, 0);
        }
    }
    #pragma unroll
    for (int ct = 0; ct < 4; ++ct) {
        const int col  = e0 + ct * 16 + r;
        const int row0 = kg * 4;
        #pragma unroll
        for (int q = 0; q < 4; ++q)
            h_lds[(row0 + q) * LDH + col] = gelu_exact(acc[ct][q]);
    }
    __syncthreads();
    const f32x4 g4 = *reinterpret_cast<const f32x4*>(&gamma[lane * 4]);
    const f32x4 b4 = *reinterpret_cast<const f32x4*>(&beta[lane * 4]);
    #pragma unroll
    for (int i = 0; i < 4; ++i) {
        const int m = wv + i * 4;
        f32x4 v = *reinterpret_cast<const f32x4*>(&h_lds[m * LDH + lane * 4]);
        float s  = v.x + v.y + v.z + v.w;
        float sq = v.x * v.x + v.y * v.y + v.z * v.z + v.w * v.w;
        #pragma unroll
        for (int off = 32; off > 0; off >>= 1) {
            s  += __shfl_xor(s, off, 64);
            sq += __shfl_xor(sq, off, 64);
        }
        const float mean = s * (1.0f / 256.0f);
        const float var  = sq * (1.0f / 256.0f) - mean * mean;
        const float rs   = rsqrtf(var + 1e-5f);
        f32x4 o = (v - mean) * rs * g4 + b4;
        *reinterpret_cast<f32x4*>(&out[((size_t)(b * TOUT) + j0 + m) * ND + lane * 4]) = o;
    }
}

extern "C" void kernel_launch(void* const* d_in, const int* in_sizes, int n_in,
                              void* d_out, int out_size, void* d_ws, size_t ws_size,
                              hipStream_t stream) {
    const float* mu    = (const float*)d_in[0];
    const int*   lens  = (const int*)d_in[1];
    const int*   olens = (const int*)d_in[2];
    const float* wf    = (const float*)d_in[3];
    const float* gamma = (const float*)d_in[4];
    const float* beta  = (const float*)d_in[5];
    float* out = (float*)d_out;

    const size_t need = (size_t)ND * ND * sizeof(unsigned short);  // 128 KB

    if (ws_size >= need) {
        unsigned short* wbF = (unsigned short*)d_ws;
        cvt_w_kernel<<<dim3(16), dim3(512), 0, stream>>>(wf, wbF);
        fused_kernel<<<dim3(NB, TOUT / TILE_M), dim3(512), 0, stream>>>(
            mu, lens, olens, wbF, gamma, beta, out);
    } else {
        fused_fallback<<<dim3(NB, TOUT / TILE_M), dim3(256), 0, stream>>>(
            mu, lens, olens, wf, gamma, beta, out);
    }
}